// Round 18
// baseline (123.925 us; speedup 1.0000x reference)
//
#include <hip/hip_runtime.h>
#include <stdint.h>

// ---- types ----
typedef __attribute__((ext_vector_type(8))) short short8;   // 8 bf16 (4 VGPRs)
typedef __attribute__((ext_vector_type(4))) float f32x4;    // MFMA acc
typedef unsigned short u16;

// B=2, S=2048, E=1024, H=16, DK=64
#define SEQ 2048
#define EMB 1024
#define NH 16
#define DK 64
#define MTOT 4096   // B*S
#define CEXP 0.18033688011112042f   // 0.125 * log2(e): fold qk-scale into exp2

__device__ __forceinline__ u16 f2bf(float f) {
  union { float f; unsigned int u; } x; x.f = f;
  unsigned int r = x.u + 0x7fffu + ((x.u >> 16) & 1u);  // RNE
  return (u16)(r >> 16);
}

// async global->LDS, 16B per lane. LDS dest = wave-uniform base + lane*16.
__device__ __forceinline__ void gload_lds16(const void* g, void* l) {
  __builtin_amdgcn_global_load_lds(
      (const __attribute__((address_space(1))) unsigned int*)g,
      (__attribute__((address_space(3))) unsigned int*)l,
      16, 0, 0);
}

// ---------------- fp32 -> bf16 convert: WEIGHTS ONLY ----------------
__global__ __launch_bounds__(256) void cvt_w(const float* __restrict__ a,
                                             const float* __restrict__ b,
                                             const float* __restrict__ c,
                                             const float* __restrict__ e,
                                             u16* __restrict__ d) {
  const float* s = (blockIdx.y == 0) ? a
                 : ((blockIdx.y == 1) ? b : ((blockIdx.y == 2) ? c : e));
  size_t base = (size_t)blockIdx.y * ((size_t)EMB * EMB / 4);
  int i = blockIdx.x * 256 + threadIdx.x;
  float4 v = ((const float4*)s)[i];
  ushort4 o;
  o.x = f2bf(v.x); o.y = f2bf(v.y); o.z = f2bf(v.z); o.w = f2bf(v.w);
  ((ushort4*)d)[base + i] = o;
}

// ------- gemm_qkv, fused fp32->bf16 A-staging, CROSS-ITERATION PREFETCH -----
// R17 lesson: all-loads-first still leaves ~650cy stall at the cvt (loads
// issued ~50cy earlier). v3: A(kt+1) loads are issued right after cvt(kt)
// frees the registers; they ride over {barrier, MFMA, barrier, B-issue} and
// land before next iteration's cvt. s_barrier only drains gload_lds/ds ops
// (shared-state), NOT register-dest loads -> prefetch survives the barriers.
// ar[4][2] (32 VGPR) live across the loop; (256,3) cap 170 still safe.
__global__ __launch_bounds__(256, 3) void gemm_qkv_f32(const float* __restrict__ qf,
                                                       const float* __restrict__ kf,
                                                       const float* __restrict__ vf,
                                                       const u16* __restrict__ Wall,
                                                       const float* __restrict__ bq,
                                                       const float* __restrict__ bk,
                                                       const float* __restrict__ bv,
                                                       u16* __restrict__ QKVh) {
  __shared__ __align__(16) u16 As[128 * 64];
  __shared__ __align__(16) u16 Bs[128 * 64];

  int bl = blockIdx.x;
  int xcd = bl & 7, i0 = bl >> 3;
  int bx = i0 & 7;                // n-panel
  int j = i0 >> 3;                // [0,12): 4 m-panels x 3 z per XCD
  int z = j >> 2;
  int by = xcd * 4 + (j & 3);
  const float* A = (z == 0) ? qf : ((z == 1) ? kf : vf);
  const u16* W = Wall + (size_t)z * EMB * EMB;
  const float* bias = (z == 0) ? bq : ((z == 1) ? bk : bv);
  u16* dst = QKVh + (size_t)z * MTOT * EMB;
  int m0 = by * 128, n0 = bx * 128;

  const int K = EMB;
  int tid = threadIdx.x, lane = tid & 63, wid = tid >> 6;
  int g = lane >> 4, l15 = lane & 15;
  int wr = wid >> 1, wc = wid & 1;

  // A-staging geometry (per it): bf16 idx = it*2048 + tid*8
  int arow = tid >> 3;            // + it*32
  int acol = (tid & 7) * 8;
  const float* abase = A + (size_t)(m0 + arow) * K + acol;

  f32x4 acc[4][4];
#pragma unroll
  for (int mi = 0; mi < 4; ++mi)
#pragma unroll
    for (int ni = 0; ni < 4; ++ni) acc[mi][ni] = (f32x4)(0.0f);

  // prologue: issue A(0) loads
  float4 ar[4][2];
#pragma unroll
  for (int it = 0; it < 4; ++it) {
    const float* ap = abase + (size_t)(it * 32) * K;
    ar[it][0] = *(const float4*)ap;
    ar[it][1] = *(const float4*)(ap + 4);
  }

  for (int kt = 0; kt < K / 64; ++kt) {
    int k0 = kt * 64;

    // --- B tile via async gload_lds (4 instrs per wave) ---
#pragma unroll
    for (int i = 0; i < 4; ++i) {
      int off = (wid * 4 + i) * 1024;          // byte offset into tile
      int elem = (off >> 1) + lane * 8;
      int row = elem >> 6, col = elem & 63;
      gload_lds16(W + (size_t)(n0 + row) * K + k0 + col, (char*)Bs + off);
    }
    // --- A: cvt + LDS write (loads issued last iteration -> landed) ---
#pragma unroll
    for (int it = 0; it < 4; ++it) {
      union { short8 s8; uint32_t w[4]; } pk;
      asm("v_cvt_pk_bf16_f32 %0, %1, %2" : "=v"(pk.w[0]) : "v"(ar[it][0].x), "v"(ar[it][0].y));
      asm("v_cvt_pk_bf16_f32 %0, %1, %2" : "=v"(pk.w[1]) : "v"(ar[it][0].z), "v"(ar[it][0].w));
      asm("v_cvt_pk_bf16_f32 %0, %1, %2" : "=v"(pk.w[2]) : "v"(ar[it][1].x), "v"(ar[it][1].y));
      asm("v_cvt_pk_bf16_f32 %0, %1, %2" : "=v"(pk.w[3]) : "v"(ar[it][1].z), "v"(ar[it][1].w));
      *(short8*)&As[it * 2048 + tid * 8] = pk.s8;
    }
    // --- issue A(kt+1) loads: ride over barrier+MFMA+barrier+B-issue ---
    if (kt < K / 64 - 1) {
      int k1 = k0 + 64;
#pragma unroll
      for (int it = 0; it < 4; ++it) {
        const float* ap = abase + (size_t)(it * 32) * K + k1;
        ar[it][0] = *(const float4*)ap;
        ar[it][1] = *(const float4*)(ap + 4);
      }
    }
    __syncthreads();  // drains B gloads + As ds_writes (NOT the A reg-loads)
#pragma unroll
    for (int kk = 0; kk < 2; ++kk) {
      short8 af[4], bf[4];
#pragma unroll
      for (int mi = 0; mi < 4; ++mi)
        af[mi] = *(const short8*)&As[(wr * 64 + mi * 16 + l15) * 64 + kk * 32 + 8 * g];
#pragma unroll
      for (int ni = 0; ni < 4; ++ni)
        bf[ni] = *(const short8*)&Bs[(wc * 64 + ni * 16 + l15) * 64 + kk * 32 + 8 * g];
#pragma unroll
      for (int mi = 0; mi < 4; ++mi)
#pragma unroll
        for (int ni = 0; ni < 4; ++ni)
          acc[mi][ni] = __builtin_amdgcn_mfma_f32_16x16x32_bf16(af[mi], bf[ni],
                                                                acc[mi][ni], 0, 0, 0);
    }
    __syncthreads();
  }

  // epilogue: D layout col=lane&15, row=(lane>>4)*4+j; store head layout bf16
#pragma unroll
  for (int ni = 0; ni < 4; ++ni) {
    int n_g = n0 + wc * 64 + ni * 16 + l15;
    float bv2 = bias[n_g];
#pragma unroll
    for (int mi = 0; mi < 4; ++mi) {
#pragma unroll
      for (int j2 = 0; j2 < 4; ++j2) {
        int m_g = m0 + wr * 64 + mi * 16 + 4 * g + j2;
        float v = acc[mi][ni][j2] + bv2;
        int b = m_g >> 11, s = m_g & (SEQ - 1);
        int h = n_g >> 6, d = n_g & 63;
        dst[((((size_t)b * NH + h) * SEQ + s) << 6) + d] = f2bf(v);
      }
    }
  }
}

// ---------------- gemm_out: C fp32 = X bf16 @ Wo^T + bias ----------------
__global__ __launch_bounds__(256, 3) void gemm_out(const u16* __restrict__ X,
                                                   const u16* __restrict__ Wo,
                                                   const float* __restrict__ bo,
                                                   float* __restrict__ out) {
  __shared__ __align__(16) u16 As[128 * 64];
  __shared__ __align__(16) u16 Bs[128 * 64];
  int bl = blockIdx.x;
  int xcd = bl & 7, i0 = bl >> 3;
  int bx = i0 & 7;                // n-panel
  int by = xcd * 4 + (i0 >> 3);   // i0>>3 in [0,4)
  int m0 = by * 128, n0 = bx * 128;

  const int K = EMB;
  int tid = threadIdx.x, lane = tid & 63, wid = tid >> 6;
  int g = lane >> 4, l15 = lane & 15;
  int wr = wid >> 1, wc = wid & 1;

  f32x4 acc[4][4];
#pragma unroll
  for (int mi = 0; mi < 4; ++mi)
#pragma unroll
    for (int ni = 0; ni < 4; ++ni) acc[mi][ni] = (f32x4)(0.0f);

  for (int kt = 0; kt < K / 64; ++kt) {
    int k0 = kt * 64;
#pragma unroll
    for (int i = 0; i < 4; ++i) {
      int off = (wid * 4 + i) * 1024;
      int elem = (off >> 1) + lane * 8;
      int row = elem >> 6, col = elem & 63;
      gload_lds16(X + (size_t)(m0 + row) * K + k0 + col, (char*)As + off);
      gload_lds16(Wo + (size_t)(n0 + row) * K + k0 + col, (char*)Bs + off);
    }
    __syncthreads();
#pragma unroll
    for (int kk = 0; kk < 2; ++kk) {
      short8 af[4], bf[4];
#pragma unroll
      for (int mi = 0; mi < 4; ++mi)
        af[mi] = *(const short8*)&As[(wr * 64 + mi * 16 + l15) * 64 + kk * 32 + 8 * g];
#pragma unroll
      for (int ni = 0; ni < 4; ++ni)
        bf[ni] = *(const short8*)&Bs[(wc * 64 + ni * 16 + l15) * 64 + kk * 32 + 8 * g];
#pragma unroll
      for (int mi = 0; mi < 4; ++mi)
#pragma unroll
        for (int ni = 0; ni < 4; ++ni)
          acc[mi][ni] = __builtin_amdgcn_mfma_f32_16x16x32_bf16(af[mi], bf[ni],
                                                                acc[mi][ni], 0, 0, 0);
    }
    __syncthreads();
  }

#pragma unroll
  for (int ni = 0; ni < 4; ++ni) {
    int n_g = n0 + wc * 64 + ni * 16 + l15;
    float bv = bo[n_g];
#pragma unroll
    for (int mi = 0; mi < 4; ++mi) {
#pragma unroll
      for (int j = 0; j < 4; ++j) {
        int m_g = m0 + wr * 64 + mi * 16 + 4 * g + j;
        out[(size_t)m_g * EMB + n_g] = acc[mi][ni][j] + bv;
      }
    }
  }
}

// ---------------- flash attention (causal), v9 (exact R10/R11 kernel) -------
__global__ __launch_bounds__(256, 4) void flash_attn(const u16* __restrict__ Qh,
                                                     const u16* __restrict__ Kh,
                                                     const u16* __restrict__ Vh,
                                                     u16* __restrict__ X) {
  __shared__ __align__(16) u16 Ks[2][64][64];   // [buf][kv][k], swz_k
  __shared__ __align__(16) u16 Vt[2][64][64];   // [buf][d][kv], swz_v

  int tid = threadIdx.x, lane = tid & 63, wid = tid >> 6;
  int g = lane >> 4, l15 = lane & 15;

  int bl = blockIdx.x;
  int xcd = bl & 7, idx = bl >> 3;
  int c = idx & 31, r = idx >> 5;
  int bh = xcd * 4 + r;                         // 4 bh per XCD -> K/V L2-resident
  int cc = (r >= 2) ? ((c + 16) & 31) : c;
  int qt = (r & 1) ? (31 - cc) : cc;            // balanced qt per CU slot

  int q0 = qt * 64, qw = q0 + wid * 16;
  int qrow = qw + l15;                          // this lane's q row

  // Q fragment (B-operand): rows q = qw+l15, k halves at +0 / +32
  const short8* qp = (const short8*)(Qh + ((size_t)bh * SEQ + qrow) * DK + 8 * g);
  short8 fq0 = qp[0], fq1 = qp[4];

  int kvbase = 8 * (l15 >> 2) + (l15 & 3);      // sigma row base for this lane
  int ksw = ((l15 & 3) | (((l15 >> 2) & 1) << 2)) << 3;   // u16 col XOR
  int vsw = (l15 & 7) << 3;                               // PV-read XOR
  const u16* Kb = Kh + (size_t)bh * SEQ * DK;
  const u16* Vb = Vh + (size_t)bh * SEQ * DK;

  // K staging geometry: 2 instrs/wave; lane covers row rw, 16B chunk (lane&7)
  int krow_st = wid * 16 + (lane >> 3);         // +8*i for i=0,1
  int kcol_st = (lane & 7) * 8;                 // u16 col (pre-swizzle)

  f32x4 sc[4], oacc[4];
#pragma unroll
  for (int i = 0; i < 4; ++i) oacc[i] = (f32x4)(0.0f);
  float m_run = -1e30f, l_part = 0.0f;

  // prologue: stage K(0), V(0) into buf 0
#pragma unroll
  for (int i = 0; i < 2; ++i) {
    int rw = krow_st + i * 8;
    int wsw = (((rw & 3) | (((rw >> 3) & 1) << 2)) << 3);
    short8 kt = *(const short8*)(Kb + (size_t)rw * DK + kcol_st);
    *(short8*)(&Ks[0][0][0] + rw * 64 + (kcol_st ^ wsw)) = kt;
  }
#pragma unroll
  for (int it2 = 0; it2 < 2; ++it2) {
    int kvb = wid * 8 + it2 * 32;
    short8 tmp;
#pragma unroll
    for (int i = 0; i < 8; ++i)
      tmp[i] = (short)Vb[(size_t)(kvb + i) * DK + lane];
    *(short8*)(&Vt[0][0][0] + lane * 64 + (kvb ^ ((lane & 7) << 3))) = tmp;
  }
  __syncthreads();

  for (int t = 0; t <= qt; ++t) {
    int kv0 = t * 64;
    int cur = t & 1;

    // T14: issue next-tile K + V global loads FIRST (hide under compute)
    short8 ktmp[2];
    u16 vtmp[16];
    if (t < qt) {
      int kvn = kv0 + 64;
#pragma unroll
      for (int i = 0; i < 2; ++i)
        ktmp[i] = *(const short8*)(Kb + (size_t)(kvn + krow_st + i * 8) * DK + kcol_st);
#pragma unroll
      for (int it2 = 0; it2 < 2; ++it2)
#pragma unroll
        for (int i = 0; i < 8; ++i)
          vtmp[it2 * 8 + i] = Vb[(size_t)(kvn + wid * 8 + it2 * 32 + i) * DK + lane];
    }

    // QK^T swapped from Ks[cur] (sigma rows; swizzled, conflict-free b128)
    {
      const u16* base = &Ks[cur][0][0];
      short8 kf[4][2];
#pragma unroll
      for (int cq = 0; cq < 4; ++cq) {
        int krow = kvbase + 4 * (cq & 1) + 32 * (cq >> 1);
        kf[cq][0] = *(const short8*)(base + krow * 64 + ((8 * g) ^ ksw));
        kf[cq][1] = *(const short8*)(base + krow * 64 + ((8 * g + 32) ^ ksw));
      }
      __builtin_amdgcn_s_setprio(1);
#pragma unroll
      for (int cq = 0; cq < 4; ++cq) {
        f32x4 z = (f32x4)(0.0f);
        z = __builtin_amdgcn_mfma_f32_16x16x32_bf16(kf[cq][0], fq0, z, 0, 0, 0);
        z = __builtin_amdgcn_mfma_f32_16x16x32_bf16(kf[cq][1], fq1, z, 0, 0, 0);
        sc[cq] = z;
      }
      __builtin_amdgcn_s_setprio(0);
    }

    // causal mask (diag tile only); sc[cq][j] is kv = kv0+8g+4(cq&1)+32(cq>>1)+j
    if (t == qt) {
#pragma unroll
      for (int cq = 0; cq < 4; ++cq) {
        int kvc = kv0 + 8 * g + 4 * (cq & 1) + 32 * (cq >> 1);
#pragma unroll
        for (int j = 0; j < 4; ++j)
          if (kvc + j > qrow) sc[cq][j] = -1e30f;
      }
    }

    // row max: 15 in-reg + 2 shfl (lanes l15, +16, +32, +48 share q)
    float vmax = sc[0][0];
#pragma unroll
    for (int cq = 0; cq < 4; ++cq)
#pragma unroll
      for (int j = 0; j < 4; ++j) vmax = fmaxf(vmax, sc[cq][j]);
    vmax = fmaxf(vmax, __shfl_xor(vmax, 16));
    vmax = fmaxf(vmax, __shfl_xor(vmax, 32));

    // defer-max (T13): raw-score threshold 44 -> p bounded by ~2^8
    if (!__all(vmax - m_run <= 44.0f)) {
      float mnew = fmaxf(m_run, vmax);
      float alpha = exp2f((m_run - mnew) * CEXP);
      l_part *= alpha;
#pragma unroll
      for (int c2 = 0; c2 < 4; ++c2)
#pragma unroll
        for (int j = 0; j < 4; ++j) oacc[c2][j] *= alpha;
      m_run = mnew;
    }

    // exp + PARTIAL row sum (reduced once in epilogue)
#pragma unroll
    for (int cq = 0; cq < 4; ++cq)
#pragma unroll
      for (int j = 0; j < 4; ++j) {
        float p = exp2f((sc[cq][j] - m_run) * CEXP);
        sc[cq][j] = p;
        l_part += p;
      }

    // pack P in-register -> PV B-fragments (kv = 32h+8g+m; m = 4(cq&1)+j)
    union { short8 s8; uint32_t w[4]; } pa[2];
#pragma unroll
    for (int h = 0; h < 2; ++h)
#pragma unroll
      for (int i = 0; i < 4; ++i) {
        float lo = sc[2 * h + (i >> 1)][(i & 1) * 2];
        float hi = sc[2 * h + (i >> 1)][(i & 1) * 2 + 1];
        asm("v_cvt_pk_bf16_f32 %0, %1, %2" : "=v"(pa[h].w[i]) : "v"(lo), "v"(hi));
      }

    // PV: O^T[d][q] += V^T-frag (A, rows=d) x P-frag (B, rows=q), from Vt[cur]
    __builtin_amdgcn_s_setprio(1);
#pragma unroll
    for (int c2 = 0; c2 < 4; ++c2)
#pragma unroll
      for (int h = 0; h < 2; ++h) {
        short8 av = *(const short8*)(&Vt[cur][0][0] + (c2 * 16 + l15) * 64 +
                                     ((h * 32 + 8 * g) ^ vsw));
        oacc[c2] = __builtin_amdgcn_mfma_f32_16x16x32_bf16(av, pa[h].s8,
                                                           oacc[c2], 0, 0, 0);
      }
    __builtin_amdgcn_s_setprio(0);

    // write staged K(t+1), V(t+1) into the other buffers, single barrier
    if (t < qt) {
#pragma unroll
      for (int i = 0; i < 2; ++i) {
        int rw = krow_st + i * 8;
        int wsw = (((rw & 3) | (((rw >> 3) & 1) << 2)) << 3);
        *(short8*)(&Ks[cur ^ 1][0][0] + rw * 64 + (kcol_st ^ wsw)) = ktmp[i];
      }
#pragma unroll
      for (int it2 = 0; it2 < 2; ++it2) {
        short8 w;
#pragma unroll
        for (int i = 0; i < 8; ++i) w[i] = (short)vtmp[it2 * 8 + i];
        int kvb = wid * 8 + it2 * 32;
        *(short8*)(&Vt[cur ^ 1][0][0] + lane * 64 + (kvb ^ ((lane & 7) << 3))) = w;
      }
    }
    __syncthreads();
  }

  // epilogue: reduce l across the 4 lanes sharing a q-row, normalize,
  // transpose through LDS (per-wave 16x64 region of Vt[0]), coalesced store
  float ls = l_part;
  ls += __shfl_xor(ls, 16);
  ls += __shfl_xor(ls, 32);
  float inv = 1.0f / ls;
  u16* ow = &Vt[0][0][0] + wid * 16 * 64;       // 16 rows x 64 per wave
#pragma unroll
  for (int c2 = 0; c2 < 4; ++c2)
#pragma unroll
    for (int jp = 0; jp < 2; ++jp) {
      float lo = oacc[c2][2 * jp] * inv, hi = oacc[c2][2 * jp + 1] * inv;
      uint32_t w;
      asm("v_cvt_pk_bf16_f32 %0, %1, %2" : "=v"(w) : "v"(lo), "v"(hi));
      *(uint32_t*)&ow[l15 * 64 + c2 * 16 + 4 * g + 2 * jp] = w;
    }
  __syncthreads();
  int rr = lane >> 2, dc = (lane & 3) * 16;
  short8 o0 = *(const short8*)&ow[rr * 64 + dc];
  short8 o1 = *(const short8*)&ow[rr * 64 + dc + 8];
  int b = bh >> 4, hh = bh & 15;
  size_t xo = ((size_t)b * SEQ + qw + rr) * EMB + hh * 64 + dc;
  *(short8*)&X[xo] = o0;
  *(short8*)&X[xo + 8] = o1;
}

// ---------------- host ----------------
extern "C" void kernel_launch(void* const* d_in, const int* in_sizes, int n_in,
                              void* d_out, int out_size, void* d_ws, size_t ws_size,
                              hipStream_t stream) {
  const float* q  = (const float*)d_in[0];
  const float* k  = (const float*)d_in[1];
  const float* v  = (const float*)d_in[2];
  const float* wq = (const float*)d_in[4];
  const float* bq = (const float*)d_in[5];
  const float* wk = (const float*)d_in[6];
  const float* bk = (const float*)d_in[7];
  const float* wv = (const float*)d_in[8];
  const float* bv = (const float*)d_in[9];
  const float* wo = (const float*)d_in[10];
  const float* bo = (const float*)d_in[11];

  u16* Wall = (u16*)d_ws;                                 // 4 x [1024,1024] bf16
  u16* QKVh = Wall + (size_t)4 * EMB * EMB;               // 3 x [B,H,S,64] bf16
  u16* Xb   = QKVh + (size_t)3 * MTOT * EMB;              // [4096,1024] bf16

  // weights fp32 -> bf16 (re-read 8x from L2 by the GEMMs, upfront is cheaper)
  cvt_w<<<dim3(EMB * EMB / 4 / 256, 4), 256, 0, stream>>>(wq, wk, wv, wo, Wall);

  // QKV projections with fused fp32->bf16 A-staging (T1 XCD-aware 1D grid)
  gemm_qkv_f32<<<768, 256, 0, stream>>>(q, k, v, Wall, bq, bk, bv, QKVh);

  // flash attention -> Xb [4096,1024] bf16 (v9, 1024 blocks)
  const u16* Qh = QKVh;
  const u16* Kh = QKVh + (size_t)MTOT * EMB;
  const u16* Vh = QKVh + (size_t)2 * MTOT * EMB;
  flash_attn<<<1024, 256, 0, stream>>>(Qh, Kh, Vh, Xb);

  // output projection -> fp32 d_out (T1 XCD-aware 1D grid)
  gemm_out<<<256, 256, 0, stream>>>(Xb, Wall + (size_t)3 * EMB * EMB, bo, (float*)d_out);
}

// Round 19
// 122.108 us; speedup vs baseline: 1.0149x; 1.0149x over previous
//
#include <hip/hip_runtime.h>
#include <stdint.h>

// ---- types ----
typedef __attribute__((ext_vector_type(8))) short short8;   // 8 bf16 (4 VGPRs)
typedef __attribute__((ext_vector_type(4))) float f32x4;    // MFMA acc
typedef unsigned short u16;

// B=2, S=2048, E=1024, H=16, DK=64
#define SEQ 2048
#define EMB 1024
#define NH 16
#define DK 64
#define MTOT 4096   // B*S
#define CEXP 0.18033688011112042f   // 0.125 * log2(e): fold qk-scale into exp2

__device__ __forceinline__ u16 f2bf(float f) {
  union { float f; unsigned int u; } x; x.f = f;
  unsigned int r = x.u + 0x7fffu + ((x.u >> 16) & 1u);  // RNE
  return (u16)(r >> 16);
}

// async global->LDS, 16B per lane. LDS dest = wave-uniform base + lane*16.
__device__ __forceinline__ void gload_lds16(const void* g, void* l) {
  __builtin_amdgcn_global_load_lds(
      (const __attribute__((address_space(1))) unsigned int*)g,
      (__attribute__((address_space(3))) unsigned int*)l,
      16, 0, 0);
}

// ---------------- fp32 -> bf16 convert: WEIGHTS ONLY ----------------
__global__ __launch_bounds__(256) void cvt_w(const float* __restrict__ a,
                                             const float* __restrict__ b,
                                             const float* __restrict__ c,
                                             const float* __restrict__ e,
                                             u16* __restrict__ d) {
  const float* s = (blockIdx.y == 0) ? a
                 : ((blockIdx.y == 1) ? b : ((blockIdx.y == 2) ? c : e));
  size_t base = (size_t)blockIdx.y * ((size_t)EMB * EMB / 4);
  int i = blockIdx.x * 256 + threadIdx.x;
  float4 v = ((const float4*)s)[i];
  ushort4 o;
  o.x = f2bf(v.x); o.y = f2bf(v.y); o.z = f2bf(v.z); o.w = f2bf(v.w);
  ((ushort4*)d)[base + i] = o;
}

// ------- gemm_qkv with fused fp32->bf16 A-staging, ALL-LOADS-FIRST -------
// (exact R17 kernel — session-best config, 122.3 us total.)
// R16 lesson: per-it load->cvt->write serialized 4 HBM round-trips per K-step.
// R17 fix: fill float4 ar[4][2] with all 8 dwordx4 FIRST, then cvt+ds_write ->
// one round-trip per step. R18's cross-iteration prefetch was neutral: hipcc
// drains vmcnt(0) at every s_barrier, so reg-prefetch can't ride over it.
__global__ __launch_bounds__(256, 3) void gemm_qkv_f32(const float* __restrict__ qf,
                                                       const float* __restrict__ kf,
                                                       const float* __restrict__ vf,
                                                       const u16* __restrict__ Wall,
                                                       const float* __restrict__ bq,
                                                       const float* __restrict__ bk,
                                                       const float* __restrict__ bv,
                                                       u16* __restrict__ QKVh) {
  __shared__ __align__(16) u16 As[128 * 64];
  __shared__ __align__(16) u16 Bs[128 * 64];

  int bl = blockIdx.x;
  int xcd = bl & 7, i0 = bl >> 3;
  int bx = i0 & 7;                // n-panel
  int j = i0 >> 3;                // [0,12): 4 m-panels x 3 z per XCD
  int z = j >> 2;
  int by = xcd * 4 + (j & 3);
  const float* A = (z == 0) ? qf : ((z == 1) ? kf : vf);
  const u16* W = Wall + (size_t)z * EMB * EMB;
  const float* bias = (z == 0) ? bq : ((z == 1) ? bk : bv);
  u16* dst = QKVh + (size_t)z * MTOT * EMB;
  int m0 = by * 128, n0 = bx * 128;

  const int K = EMB;
  int tid = threadIdx.x, lane = tid & 63, wid = tid >> 6;
  int g = lane >> 4, l15 = lane & 15;
  int wr = wid >> 1, wc = wid & 1;

  // A-staging geometry (per it): bf16 idx = it*2048 + tid*8
  int arow = tid >> 3;            // + it*32
  int acol = (tid & 7) * 8;
  const float* abase = A + (size_t)(m0 + arow) * K + acol;

  f32x4 acc[4][4];
#pragma unroll
  for (int mi = 0; mi < 4; ++mi)
#pragma unroll
    for (int ni = 0; ni < 4; ++ni) acc[mi][ni] = (f32x4)(0.0f);

  for (int kt = 0; kt < K / 64; ++kt) {
    int k0 = kt * 64;

    // --- A: issue ALL 8 fp32 loads first (one HBM round-trip per step) ---
    float4 ar[4][2];
#pragma unroll
    for (int it = 0; it < 4; ++it) {
      const float* ap = abase + (size_t)(it * 32) * K + k0;
      ar[it][0] = *(const float4*)ap;
      ar[it][1] = *(const float4*)(ap + 4);
    }
    // --- B tile via async gload_lds (4 instrs per wave) ---
#pragma unroll
    for (int i = 0; i < 4; ++i) {
      int off = (wid * 4 + i) * 1024;          // byte offset into tile
      int elem = (off >> 1) + lane * 8;
      int row = elem >> 6, col = elem & 63;
      gload_lds16(W + (size_t)(n0 + row) * K + k0 + col, (char*)Bs + off);
    }
    // --- A: cvt + LDS write (loads have had the B-issue window to land) ---
#pragma unroll
    for (int it = 0; it < 4; ++it) {
      union { short8 s8; uint32_t w[4]; } pk;
      asm("v_cvt_pk_bf16_f32 %0, %1, %2" : "=v"(pk.w[0]) : "v"(ar[it][0].x), "v"(ar[it][0].y));
      asm("v_cvt_pk_bf16_f32 %0, %1, %2" : "=v"(pk.w[1]) : "v"(ar[it][0].z), "v"(ar[it][0].w));
      asm("v_cvt_pk_bf16_f32 %0, %1, %2" : "=v"(pk.w[2]) : "v"(ar[it][1].x), "v"(ar[it][1].y));
      asm("v_cvt_pk_bf16_f32 %0, %1, %2" : "=v"(pk.w[3]) : "v"(ar[it][1].z), "v"(ar[it][1].w));
      *(short8*)&As[it * 2048 + tid * 8] = pk.s8;
    }
    __syncthreads();  // drains vmcnt + lgkm
#pragma unroll
    for (int kk = 0; kk < 2; ++kk) {
      short8 af[4], bf[4];
#pragma unroll
      for (int mi = 0; mi < 4; ++mi)
        af[mi] = *(const short8*)&As[(wr * 64 + mi * 16 + l15) * 64 + kk * 32 + 8 * g];
#pragma unroll
      for (int ni = 0; ni < 4; ++ni)
        bf[ni] = *(const short8*)&Bs[(wc * 64 + ni * 16 + l15) * 64 + kk * 32 + 8 * g];
#pragma unroll
      for (int mi = 0; mi < 4; ++mi)
#pragma unroll
        for (int ni = 0; ni < 4; ++ni)
          acc[mi][ni] = __builtin_amdgcn_mfma_f32_16x16x32_bf16(af[mi], bf[ni],
                                                                acc[mi][ni], 0, 0, 0);
    }
    __syncthreads();
  }

  // epilogue: D layout col=lane&15, row=(lane>>4)*4+j; store head layout bf16
#pragma unroll
  for (int ni = 0; ni < 4; ++ni) {
    int n_g = n0 + wc * 64 + ni * 16 + l15;
    float bv2 = bias[n_g];
#pragma unroll
    for (int mi = 0; mi < 4; ++mi) {
#pragma unroll
      for (int j2 = 0; j2 < 4; ++j2) {
        int m_g = m0 + wr * 64 + mi * 16 + 4 * g + j2;
        float v = acc[mi][ni][j2] + bv2;
        int b = m_g >> 11, s = m_g & (SEQ - 1);
        int h = n_g >> 6, d = n_g & 63;
        dst[((((size_t)b * NH + h) * SEQ + s) << 6) + d] = f2bf(v);
      }
    }
  }
}

// ---------------- gemm_out: C fp32 = X bf16 @ Wo^T + bias ----------------
__global__ __launch_bounds__(256, 3) void gemm_out(const u16* __restrict__ X,
                                                   const u16* __restrict__ Wo,
                                                   const float* __restrict__ bo,
                                                   float* __restrict__ out) {
  __shared__ __align__(16) u16 As[128 * 64];
  __shared__ __align__(16) u16 Bs[128 * 64];
  int bl = blockIdx.x;
  int xcd = bl & 7, i0 = bl >> 3;
  int bx = i0 & 7;                // n-panel
  int by = xcd * 4 + (i0 >> 3);   // i0>>3 in [0,4)
  int m0 = by * 128, n0 = bx * 128;

  const int K = EMB;
  int tid = threadIdx.x, lane = tid & 63, wid = tid >> 6;
  int g = lane >> 4, l15 = lane & 15;
  int wr = wid >> 1, wc = wid & 1;

  f32x4 acc[4][4];
#pragma unroll
  for (int mi = 0; mi < 4; ++mi)
#pragma unroll
    for (int ni = 0; ni < 4; ++ni) acc[mi][ni] = (f32x4)(0.0f);

  for (int kt = 0; kt < K / 64; ++kt) {
    int k0 = kt * 64;
#pragma unroll
    for (int i = 0; i < 4; ++i) {
      int off = (wid * 4 + i) * 1024;
      int elem = (off >> 1) + lane * 8;
      int row = elem >> 6, col = elem & 63;
      gload_lds16(X + (size_t)(m0 + row) * K + k0 + col, (char*)As + off);
      gload_lds16(Wo + (size_t)(n0 + row) * K + k0 + col, (char*)Bs + off);
    }
    __syncthreads();
#pragma unroll
    for (int kk = 0; kk < 2; ++kk) {
      short8 af[4], bf[4];
#pragma unroll
      for (int mi = 0; mi < 4; ++mi)
        af[mi] = *(const short8*)&As[(wr * 64 + mi * 16 + l15) * 64 + kk * 32 + 8 * g];
#pragma unroll
      for (int ni = 0; ni < 4; ++ni)
        bf[ni] = *(const short8*)&Bs[(wc * 64 + ni * 16 + l15) * 64 + kk * 32 + 8 * g];
#pragma unroll
      for (int mi = 0; mi < 4; ++mi)
#pragma unroll
        for (int ni = 0; ni < 4; ++ni)
          acc[mi][ni] = __builtin_amdgcn_mfma_f32_16x16x32_bf16(af[mi], bf[ni],
                                                                acc[mi][ni], 0, 0, 0);
    }
    __syncthreads();
  }

#pragma unroll
  for (int ni = 0; ni < 4; ++ni) {
    int n_g = n0 + wc * 64 + ni * 16 + l15;
    float bv = bo[n_g];
#pragma unroll
    for (int mi = 0; mi < 4; ++mi) {
#pragma unroll
      for (int j = 0; j < 4; ++j) {
        int m_g = m0 + wr * 64 + mi * 16 + 4 * g + j;
        out[(size_t)m_g * EMB + n_g] = acc[mi][ni][j] + bv;
      }
    }
  }
}

// ---------------- flash attention (causal), v9 (exact R10/R11 kernel) -------
__global__ __launch_bounds__(256, 4) void flash_attn(const u16* __restrict__ Qh,
                                                     const u16* __restrict__ Kh,
                                                     const u16* __restrict__ Vh,
                                                     u16* __restrict__ X) {
  __shared__ __align__(16) u16 Ks[2][64][64];   // [buf][kv][k], swz_k
  __shared__ __align__(16) u16 Vt[2][64][64];   // [buf][d][kv], swz_v

  int tid = threadIdx.x, lane = tid & 63, wid = tid >> 6;
  int g = lane >> 4, l15 = lane & 15;

  int bl = blockIdx.x;
  int xcd = bl & 7, idx = bl >> 3;
  int c = idx & 31, r = idx >> 5;
  int bh = xcd * 4 + r;                         // 4 bh per XCD -> K/V L2-resident
  int cc = (r >= 2) ? ((c + 16) & 31) : c;
  int qt = (r & 1) ? (31 - cc) : cc;            // balanced qt per CU slot

  int q0 = qt * 64, qw = q0 + wid * 16;
  int qrow = qw + l15;                          // this lane's q row

  // Q fragment (B-operand): rows q = qw+l15, k halves at +0 / +32
  const short8* qp = (const short8*)(Qh + ((size_t)bh * SEQ + qrow) * DK + 8 * g);
  short8 fq0 = qp[0], fq1 = qp[4];

  int kvbase = 8 * (l15 >> 2) + (l15 & 3);      // sigma row base for this lane
  int ksw = ((l15 & 3) | (((l15 >> 2) & 1) << 2)) << 3;   // u16 col XOR
  int vsw = (l15 & 7) << 3;                               // PV-read XOR
  const u16* Kb = Kh + (size_t)bh * SEQ * DK;
  const u16* Vb = Vh + (size_t)bh * SEQ * DK;

  // K staging geometry: 2 instrs/wave; lane covers row rw, 16B chunk (lane&7)
  int krow_st = wid * 16 + (lane >> 3);         // +8*i for i=0,1
  int kcol_st = (lane & 7) * 8;                 // u16 col (pre-swizzle)

  f32x4 sc[4], oacc[4];
#pragma unroll
  for (int i = 0; i < 4; ++i) oacc[i] = (f32x4)(0.0f);
  float m_run = -1e30f, l_part = 0.0f;

  // prologue: stage K(0), V(0) into buf 0
#pragma unroll
  for (int i = 0; i < 2; ++i) {
    int rw = krow_st + i * 8;
    int wsw = (((rw & 3) | (((rw >> 3) & 1) << 2)) << 3);
    short8 kt = *(const short8*)(Kb + (size_t)rw * DK + kcol_st);
    *(short8*)(&Ks[0][0][0] + rw * 64 + (kcol_st ^ wsw)) = kt;
  }
#pragma unroll
  for (int it2 = 0; it2 < 2; ++it2) {
    int kvb = wid * 8 + it2 * 32;
    short8 tmp;
#pragma unroll
    for (int i = 0; i < 8; ++i)
      tmp[i] = (short)Vb[(size_t)(kvb + i) * DK + lane];
    *(short8*)(&Vt[0][0][0] + lane * 64 + (kvb ^ ((lane & 7) << 3))) = tmp;
  }
  __syncthreads();

  for (int t = 0; t <= qt; ++t) {
    int kv0 = t * 64;
    int cur = t & 1;

    // T14: issue next-tile K + V global loads FIRST (hide under compute)
    short8 ktmp[2];
    u16 vtmp[16];
    if (t < qt) {
      int kvn = kv0 + 64;
#pragma unroll
      for (int i = 0; i < 2; ++i)
        ktmp[i] = *(const short8*)(Kb + (size_t)(kvn + krow_st + i * 8) * DK + kcol_st);
#pragma unroll
      for (int it2 = 0; it2 < 2; ++it2)
#pragma unroll
        for (int i = 0; i < 8; ++i)
          vtmp[it2 * 8 + i] = Vb[(size_t)(kvn + wid * 8 + it2 * 32 + i) * DK + lane];
    }

    // QK^T swapped from Ks[cur] (sigma rows; swizzled, conflict-free b128)
    {
      const u16* base = &Ks[cur][0][0];
      short8 kf[4][2];
#pragma unroll
      for (int cq = 0; cq < 4; ++cq) {
        int krow = kvbase + 4 * (cq & 1) + 32 * (cq >> 1);
        kf[cq][0] = *(const short8*)(base + krow * 64 + ((8 * g) ^ ksw));
        kf[cq][1] = *(const short8*)(base + krow * 64 + ((8 * g + 32) ^ ksw));
      }
      __builtin_amdgcn_s_setprio(1);
#pragma unroll
      for (int cq = 0; cq < 4; ++cq) {
        f32x4 z = (f32x4)(0.0f);
        z = __builtin_amdgcn_mfma_f32_16x16x32_bf16(kf[cq][0], fq0, z, 0, 0, 0);
        z = __builtin_amdgcn_mfma_f32_16x16x32_bf16(kf[cq][1], fq1, z, 0, 0, 0);
        sc[cq] = z;
      }
      __builtin_amdgcn_s_setprio(0);
    }

    // causal mask (diag tile only); sc[cq][j] is kv = kv0+8g+4(cq&1)+32(cq>>1)+j
    if (t == qt) {
#pragma unroll
      for (int cq = 0; cq < 4; ++cq) {
        int kvc = kv0 + 8 * g + 4 * (cq & 1) + 32 * (cq >> 1);
#pragma unroll
        for (int j = 0; j < 4; ++j)
          if (kvc + j > qrow) sc[cq][j] = -1e30f;
      }
    }

    // row max: 15 in-reg + 2 shfl (lanes l15, +16, +32, +48 share q)
    float vmax = sc[0][0];
#pragma unroll
    for (int cq = 0; cq < 4; ++cq)
#pragma unroll
      for (int j = 0; j < 4; ++j) vmax = fmaxf(vmax, sc[cq][j]);
    vmax = fmaxf(vmax, __shfl_xor(vmax, 16));
    vmax = fmaxf(vmax, __shfl_xor(vmax, 32));

    // defer-max (T13): raw-score threshold 44 -> p bounded by ~2^8
    if (!__all(vmax - m_run <= 44.0f)) {
      float mnew = fmaxf(m_run, vmax);
      float alpha = exp2f((m_run - mnew) * CEXP);
      l_part *= alpha;
#pragma unroll
      for (int c2 = 0; c2 < 4; ++c2)
#pragma unroll
        for (int j = 0; j < 4; ++j) oacc[c2][j] *= alpha;
      m_run = mnew;
    }

    // exp + PARTIAL row sum (reduced once in epilogue)
#pragma unroll
    for (int cq = 0; cq < 4; ++cq)
#pragma unroll
      for (int j = 0; j < 4; ++j) {
        float p = exp2f((sc[cq][j] - m_run) * CEXP);
        sc[cq][j] = p;
        l_part += p;
      }

    // pack P in-register -> PV B-fragments (kv = 32h+8g+m; m = 4(cq&1)+j)
    union { short8 s8; uint32_t w[4]; } pa[2];
#pragma unroll
    for (int h = 0; h < 2; ++h)
#pragma unroll
      for (int i = 0; i < 4; ++i) {
        float lo = sc[2 * h + (i >> 1)][(i & 1) * 2];
        float hi = sc[2 * h + (i >> 1)][(i & 1) * 2 + 1];
        asm("v_cvt_pk_bf16_f32 %0, %1, %2" : "=v"(pa[h].w[i]) : "v"(lo), "v"(hi));
      }

    // PV: O^T[d][q] += V^T-frag (A, rows=d) x P-frag (B, rows=q), from Vt[cur]
    __builtin_amdgcn_s_setprio(1);
#pragma unroll
    for (int c2 = 0; c2 < 4; ++c2)
#pragma unroll
      for (int h = 0; h < 2; ++h) {
        short8 av = *(const short8*)(&Vt[cur][0][0] + (c2 * 16 + l15) * 64 +
                                     ((h * 32 + 8 * g) ^ vsw));
        oacc[c2] = __builtin_amdgcn_mfma_f32_16x16x32_bf16(av, pa[h].s8,
                                                           oacc[c2], 0, 0, 0);
      }
    __builtin_amdgcn_s_setprio(0);

    // write staged K(t+1), V(t+1) into the other buffers, single barrier
    if (t < qt) {
#pragma unroll
      for (int i = 0; i < 2; ++i) {
        int rw = krow_st + i * 8;
        int wsw = (((rw & 3) | (((rw >> 3) & 1) << 2)) << 3);
        *(short8*)(&Ks[cur ^ 1][0][0] + rw * 64 + (kcol_st ^ wsw)) = ktmp[i];
      }
#pragma unroll
      for (int it2 = 0; it2 < 2; ++it2) {
        short8 w;
#pragma unroll
        for (int i = 0; i < 8; ++i) w[i] = (short)vtmp[it2 * 8 + i];
        int kvb = wid * 8 + it2 * 32;
        *(short8*)(&Vt[cur ^ 1][0][0] + lane * 64 + (kvb ^ ((lane & 7) << 3))) = w;
      }
    }
    __syncthreads();
  }

  // epilogue: reduce l across the 4 lanes sharing a q-row, normalize,
  // transpose through LDS (per-wave 16x64 region of Vt[0]), coalesced store
  float ls = l_part;
  ls += __shfl_xor(ls, 16);
  ls += __shfl_xor(ls, 32);
  float inv = 1.0f / ls;
  u16* ow = &Vt[0][0][0] + wid * 16 * 64;       // 16 rows x 64 per wave
#pragma unroll
  for (int c2 = 0; c2 < 4; ++c2)
#pragma unroll
    for (int jp = 0; jp < 2; ++jp) {
      float lo = oacc[c2][2 * jp] * inv, hi = oacc[c2][2 * jp + 1] * inv;
      uint32_t w;
      asm("v_cvt_pk_bf16_f32 %0, %1, %2" : "=v"(w) : "v"(lo), "v"(hi));
      *(uint32_t*)&ow[l15 * 64 + c2 * 16 + 4 * g + 2 * jp] = w;
    }
  __syncthreads();
  int rr = lane >> 2, dc = (lane & 3) * 16;
  short8 o0 = *(const short8*)&ow[rr * 64 + dc];
  short8 o1 = *(const short8*)&ow[rr * 64 + dc + 8];
  int b = bh >> 4, hh = bh & 15;
  size_t xo = ((size_t)b * SEQ + qw + rr) * EMB + hh * 64 + dc;
  *(short8*)&X[xo] = o0;
  *(short8*)&X[xo + 8] = o1;
}

// ---------------- host ----------------
extern "C" void kernel_launch(void* const* d_in, const int* in_sizes, int n_in,
                              void* d_out, int out_size, void* d_ws, size_t ws_size,
                              hipStream_t stream) {
  const float* q  = (const float*)d_in[0];
  const float* k  = (const float*)d_in[1];
  const float* v  = (const float*)d_in[2];
  const float* wq = (const float*)d_in[4];
  const float* bq = (const float*)d_in[5];
  const float* wk = (const float*)d_in[6];
  const float* bk = (const float*)d_in[7];
  const float* wv = (const float*)d_in[8];
  const float* bv = (const float*)d_in[9];
  const float* wo = (const float*)d_in[10];
  const float* bo = (const float*)d_in[11];

  u16* Wall = (u16*)d_ws;                                 // 4 x [1024,1024] bf16
  u16* QKVh = Wall + (size_t)4 * EMB * EMB;               // 3 x [B,H,S,64] bf16
  u16* Xb   = QKVh + (size_t)3 * MTOT * EMB;              // [4096,1024] bf16

  // weights fp32 -> bf16 (re-read 8x from L2 by the GEMMs, upfront is cheaper)
  cvt_w<<<dim3(EMB * EMB / 4 / 256, 4), 256, 0, stream>>>(wq, wk, wv, wo, Wall);

  // QKV projections with fused fp32->bf16 A-staging (T1 XCD-aware 1D grid)
  gemm_qkv_f32<<<768, 256, 0, stream>>>(q, k, v, Wall, bq, bk, bv, QKVh);

  // flash attention -> Xb [4096,1024] bf16 (v9, 1024 blocks)
  const u16* Qh = QKVh;
  const u16* Kh = QKVh + (size_t)MTOT * EMB;
  const u16* Vh = QKVh + (size_t)2 * MTOT * EMB;
  flash_attn<<<1024, 256, 0, stream>>>(Qh, Kh, Vh, Xb);

  // output projection -> fp32 d_out (T1 XCD-aware 1D grid)
  gemm_out<<<256, 256, 0, stream>>>(Xb, Wall + (size_t)3 * EMB * EMB, bo, (float*)d_out);
}

// Round 20
// 118.847 us; speedup vs baseline: 1.0427x; 1.0274x over previous
//
#include <hip/hip_runtime.h>
#include <stdint.h>

// ---- types ----
typedef __attribute__((ext_vector_type(8))) short short8;   // 8 bf16 (4 VGPRs)
typedef __attribute__((ext_vector_type(4))) float f32x4;    // MFMA acc
typedef unsigned short u16;

// B=2, S=2048, E=1024, H=16, DK=64
#define SEQ 2048
#define EMB 1024
#define NH 16
#define DK 64
#define MTOT 4096   // B*S
#define CEXP 0.18033688011112042f   // 0.125 * log2(e): fold qk-scale into exp2

__device__ __forceinline__ u16 f2bf(float f) {
  union { float f; unsigned int u; } x; x.f = f;
  unsigned int r = x.u + 0x7fffu + ((x.u >> 16) & 1u);  // RNE
  return (u16)(r >> 16);
}

// async global->LDS, 16B per lane. LDS dest = wave-uniform base + lane*16.
__device__ __forceinline__ void gload_lds16(const void* g, void* l) {
  __builtin_amdgcn_global_load_lds(
      (const __attribute__((address_space(1))) unsigned int*)g,
      (__attribute__((address_space(3))) unsigned int*)l,
      16, 0, 0);
}

// ---------------- fp32 -> bf16 convert: WEIGHTS ONLY ----------------
__global__ __launch_bounds__(256) void cvt_w(const float* __restrict__ a,
                                             const float* __restrict__ b,
                                             const float* __restrict__ c,
                                             const float* __restrict__ e,
                                             u16* __restrict__ d) {
  const float* s = (blockIdx.y == 0) ? a
                 : ((blockIdx.y == 1) ? b : ((blockIdx.y == 2) ? c : e));
  size_t base = (size_t)blockIdx.y * ((size_t)EMB * EMB / 4);
  int i = blockIdx.x * 256 + threadIdx.x;
  float4 v = ((const float4*)s)[i];
  ushort4 o;
  o.x = f2bf(v.x); o.y = f2bf(v.y); o.z = f2bf(v.z); o.w = f2bf(v.w);
  ((ushort4*)d)[base + i] = o;
}

// ------- gemm_qkv with fused fp32->bf16 A-staging, ALL-LOADS-FIRST -------
// (exact R17 kernel — session-best config.)
__global__ __launch_bounds__(256, 3) void gemm_qkv_f32(const float* __restrict__ qf,
                                                       const float* __restrict__ kf,
                                                       const float* __restrict__ vf,
                                                       const u16* __restrict__ Wall,
                                                       const float* __restrict__ bq,
                                                       const float* __restrict__ bk,
                                                       const float* __restrict__ bv,
                                                       u16* __restrict__ QKVh) {
  __shared__ __align__(16) u16 As[128 * 64];
  __shared__ __align__(16) u16 Bs[128 * 64];

  int bl = blockIdx.x;
  int xcd = bl & 7, i0 = bl >> 3;
  int bx = i0 & 7;                // n-panel
  int j = i0 >> 3;                // [0,12): 4 m-panels x 3 z per XCD
  int z = j >> 2;
  int by = xcd * 4 + (j & 3);
  const float* A = (z == 0) ? qf : ((z == 1) ? kf : vf);
  const u16* W = Wall + (size_t)z * EMB * EMB;
  const float* bias = (z == 0) ? bq : ((z == 1) ? bk : bv);
  u16* dst = QKVh + (size_t)z * MTOT * EMB;
  int m0 = by * 128, n0 = bx * 128;

  const int K = EMB;
  int tid = threadIdx.x, lane = tid & 63, wid = tid >> 6;
  int g = lane >> 4, l15 = lane & 15;
  int wr = wid >> 1, wc = wid & 1;

  // A-staging geometry (per it): bf16 idx = it*2048 + tid*8
  int arow = tid >> 3;            // + it*32
  int acol = (tid & 7) * 8;
  const float* abase = A + (size_t)(m0 + arow) * K + acol;

  f32x4 acc[4][4];
#pragma unroll
  for (int mi = 0; mi < 4; ++mi)
#pragma unroll
    for (int ni = 0; ni < 4; ++ni) acc[mi][ni] = (f32x4)(0.0f);

  for (int kt = 0; kt < K / 64; ++kt) {
    int k0 = kt * 64;

    // --- A: issue ALL 8 fp32 loads first (one HBM round-trip per step) ---
    float4 ar[4][2];
#pragma unroll
    for (int it = 0; it < 4; ++it) {
      const float* ap = abase + (size_t)(it * 32) * K + k0;
      ar[it][0] = *(const float4*)ap;
      ar[it][1] = *(const float4*)(ap + 4);
    }
    // --- B tile via async gload_lds (4 instrs per wave) ---
#pragma unroll
    for (int i = 0; i < 4; ++i) {
      int off = (wid * 4 + i) * 1024;          // byte offset into tile
      int elem = (off >> 1) + lane * 8;
      int row = elem >> 6, col = elem & 63;
      gload_lds16(W + (size_t)(n0 + row) * K + k0 + col, (char*)Bs + off);
    }
    // --- A: cvt + LDS write (loads have had the B-issue window to land) ---
#pragma unroll
    for (int it = 0; it < 4; ++it) {
      union { short8 s8; uint32_t w[4]; } pk;
      asm("v_cvt_pk_bf16_f32 %0, %1, %2" : "=v"(pk.w[0]) : "v"(ar[it][0].x), "v"(ar[it][0].y));
      asm("v_cvt_pk_bf16_f32 %0, %1, %2" : "=v"(pk.w[1]) : "v"(ar[it][0].z), "v"(ar[it][0].w));
      asm("v_cvt_pk_bf16_f32 %0, %1, %2" : "=v"(pk.w[2]) : "v"(ar[it][1].x), "v"(ar[it][1].y));
      asm("v_cvt_pk_bf16_f32 %0, %1, %2" : "=v"(pk.w[3]) : "v"(ar[it][1].z), "v"(ar[it][1].w));
      *(short8*)&As[it * 2048 + tid * 8] = pk.s8;
    }
    __syncthreads();  // drains vmcnt + lgkm
#pragma unroll
    for (int kk = 0; kk < 2; ++kk) {
      short8 af[4], bf[4];
#pragma unroll
      for (int mi = 0; mi < 4; ++mi)
        af[mi] = *(const short8*)&As[(wr * 64 + mi * 16 + l15) * 64 + kk * 32 + 8 * g];
#pragma unroll
      for (int ni = 0; ni < 4; ++ni)
        bf[ni] = *(const short8*)&Bs[(wc * 64 + ni * 16 + l15) * 64 + kk * 32 + 8 * g];
#pragma unroll
      for (int mi = 0; mi < 4; ++mi)
#pragma unroll
        for (int ni = 0; ni < 4; ++ni)
          acc[mi][ni] = __builtin_amdgcn_mfma_f32_16x16x32_bf16(af[mi], bf[ni],
                                                                acc[mi][ni], 0, 0, 0);
    }
    __syncthreads();
  }

  // epilogue: D layout col=lane&15, row=(lane>>4)*4+j; store head layout bf16
#pragma unroll
  for (int ni = 0; ni < 4; ++ni) {
    int n_g = n0 + wc * 64 + ni * 16 + l15;
    float bv2 = bias[n_g];
#pragma unroll
    for (int mi = 0; mi < 4; ++mi) {
#pragma unroll
      for (int j2 = 0; j2 < 4; ++j2) {
        int m_g = m0 + wr * 64 + mi * 16 + 4 * g + j2;
        float v = acc[mi][ni][j2] + bv2;
        int b = m_g >> 11, s = m_g & (SEQ - 1);
        int h = n_g >> 6, d = n_g & 63;
        dst[((((size_t)b * NH + h) * SEQ + s) << 6) + d] = f2bf(v);
      }
    }
  }
}

// ---------------- gemm_out: C fp32 = X bf16 @ Wo^T + bias, BM=64 ------------
// v2: BM 128->64 => 512 blocks = 2 blocks/CU (was 1) so two blocks' staging
// and MFMA phases interleave. Wave-tile 32x64 (acc[2][4], ~45 VGPR). Per-XCD
// working set: A 8x64x2KB = 1MB + B 2MB = 3MB < 4MB L2 (8 M-panels per XCD).
__global__ __launch_bounds__(256, 4) void gemm_out(const u16* __restrict__ X,
                                                   const u16* __restrict__ Wo,
                                                   const float* __restrict__ bo,
                                                   float* __restrict__ out) {
  __shared__ __align__(16) u16 As[64 * 64];
  __shared__ __align__(16) u16 Bs[128 * 64];
  int bl = blockIdx.x;
  int xcd = bl & 7, i0 = bl >> 3;               // i0 in [0,64)
  int bx = i0 & 7;                              // n-panel
  int by = xcd * 8 + (i0 >> 3);                 // m-panel 0..63, 8 per XCD
  int m0 = by * 64, n0 = bx * 128;

  const int K = EMB;
  int tid = threadIdx.x, lane = tid & 63, wid = tid >> 6;
  int g = lane >> 4, l15 = lane & 15;
  int wr = wid >> 1, wc = wid & 1;              // wave-tile 32x64 at (wr,wc)

  f32x4 acc[2][4];
#pragma unroll
  for (int mi = 0; mi < 2; ++mi)
#pragma unroll
    for (int ni = 0; ni < 4; ++ni) acc[mi][ni] = (f32x4)(0.0f);

  for (int kt = 0; kt < K / 64; ++kt) {
    int k0 = kt * 64;
    // A tile 64x64 (8KB): 2 gload_lds per wave; B tile 128x64: 4 per wave
#pragma unroll
    for (int i = 0; i < 2; ++i) {
      int off = (wid * 2 + i) * 1024;
      int elem = (off >> 1) + lane * 8;
      int row = elem >> 6, col = elem & 63;
      gload_lds16(X + (size_t)(m0 + row) * K + k0 + col, (char*)As + off);
    }
#pragma unroll
    for (int i = 0; i < 4; ++i) {
      int off = (wid * 4 + i) * 1024;
      int elem = (off >> 1) + lane * 8;
      int row = elem >> 6, col = elem & 63;
      gload_lds16(Wo + (size_t)(n0 + row) * K + k0 + col, (char*)Bs + off);
    }
    __syncthreads();
#pragma unroll
    for (int kk = 0; kk < 2; ++kk) {
      short8 af[2], bf[4];
#pragma unroll
      for (int mi = 0; mi < 2; ++mi)
        af[mi] = *(const short8*)&As[(wr * 32 + mi * 16 + l15) * 64 + kk * 32 + 8 * g];
#pragma unroll
      for (int ni = 0; ni < 4; ++ni)
        bf[ni] = *(const short8*)&Bs[(wc * 64 + ni * 16 + l15) * 64 + kk * 32 + 8 * g];
#pragma unroll
      for (int mi = 0; mi < 2; ++mi)
#pragma unroll
        for (int ni = 0; ni < 4; ++ni)
          acc[mi][ni] = __builtin_amdgcn_mfma_f32_16x16x32_bf16(af[mi], bf[ni],
                                                                acc[mi][ni], 0, 0, 0);
    }
    __syncthreads();
  }

#pragma unroll
  for (int ni = 0; ni < 4; ++ni) {
    int n_g = n0 + wc * 64 + ni * 16 + l15;
    float bv = bo[n_g];
#pragma unroll
    for (int mi = 0; mi < 2; ++mi) {
#pragma unroll
      for (int j = 0; j < 4; ++j) {
        int m_g = m0 + wr * 32 + mi * 16 + 4 * g + j;
        out[(size_t)m_g * EMB + n_g] = acc[mi][ni][j] + bv;
      }
    }
  }
}

// ---------------- flash attention (causal), v9 (exact R10/R11 kernel) -------
__global__ __launch_bounds__(256, 4) void flash_attn(const u16* __restrict__ Qh,
                                                     const u16* __restrict__ Kh,
                                                     const u16* __restrict__ Vh,
                                                     u16* __restrict__ X) {
  __shared__ __align__(16) u16 Ks[2][64][64];   // [buf][kv][k], swz_k
  __shared__ __align__(16) u16 Vt[2][64][64];   // [buf][d][kv], swz_v

  int tid = threadIdx.x, lane = tid & 63, wid = tid >> 6;
  int g = lane >> 4, l15 = lane & 15;

  int bl = blockIdx.x;
  int xcd = bl & 7, idx = bl >> 3;
  int c = idx & 31, r = idx >> 5;
  int bh = xcd * 4 + r;                         // 4 bh per XCD -> K/V L2-resident
  int cc = (r >= 2) ? ((c + 16) & 31) : c;
  int qt = (r & 1) ? (31 - cc) : cc;            // balanced qt per CU slot

  int q0 = qt * 64, qw = q0 + wid * 16;
  int qrow = qw + l15;                          // this lane's q row

  // Q fragment (B-operand): rows q = qw+l15, k halves at +0 / +32
  const short8* qp = (const short8*)(Qh + ((size_t)bh * SEQ + qrow) * DK + 8 * g);
  short8 fq0 = qp[0], fq1 = qp[4];

  int kvbase = 8 * (l15 >> 2) + (l15 & 3);      // sigma row base for this lane
  int ksw = ((l15 & 3) | (((l15 >> 2) & 1) << 2)) << 3;   // u16 col XOR
  int vsw = (l15 & 7) << 3;                               // PV-read XOR
  const u16* Kb = Kh + (size_t)bh * SEQ * DK;
  const u16* Vb = Vh + (size_t)bh * SEQ * DK;

  // K staging geometry: 2 instrs/wave; lane covers row rw, 16B chunk (lane&7)
  int krow_st = wid * 16 + (lane >> 3);         // +8*i for i=0,1
  int kcol_st = (lane & 7) * 8;                 // u16 col (pre-swizzle)

  f32x4 sc[4], oacc[4];
#pragma unroll
  for (int i = 0; i < 4; ++i) oacc[i] = (f32x4)(0.0f);
  float m_run = -1e30f, l_part = 0.0f;

  // prologue: stage K(0), V(0) into buf 0
#pragma unroll
  for (int i = 0; i < 2; ++i) {
    int rw = krow_st + i * 8;
    int wsw = (((rw & 3) | (((rw >> 3) & 1) << 2)) << 3);
    short8 kt = *(const short8*)(Kb + (size_t)rw * DK + kcol_st);
    *(short8*)(&Ks[0][0][0] + rw * 64 + (kcol_st ^ wsw)) = kt;
  }
#pragma unroll
  for (int it2 = 0; it2 < 2; ++it2) {
    int kvb = wid * 8 + it2 * 32;
    short8 tmp;
#pragma unroll
    for (int i = 0; i < 8; ++i)
      tmp[i] = (short)Vb[(size_t)(kvb + i) * DK + lane];
    *(short8*)(&Vt[0][0][0] + lane * 64 + (kvb ^ ((lane & 7) << 3))) = tmp;
  }
  __syncthreads();

  for (int t = 0; t <= qt; ++t) {
    int kv0 = t * 64;
    int cur = t & 1;

    // T14: issue next-tile K + V global loads FIRST (hide under compute)
    short8 ktmp[2];
    u16 vtmp[16];
    if (t < qt) {
      int kvn = kv0 + 64;
#pragma unroll
      for (int i = 0; i < 2; ++i)
        ktmp[i] = *(const short8*)(Kb + (size_t)(kvn + krow_st + i * 8) * DK + kcol_st);
#pragma unroll
      for (int it2 = 0; it2 < 2; ++it2)
#pragma unroll
        for (int i = 0; i < 8; ++i)
          vtmp[it2 * 8 + i] = Vb[(size_t)(kvn + wid * 8 + it2 * 32 + i) * DK + lane];
    }

    // QK^T swapped from Ks[cur] (sigma rows; swizzled, conflict-free b128)
    {
      const u16* base = &Ks[cur][0][0];
      short8 kf[4][2];
#pragma unroll
      for (int cq = 0; cq < 4; ++cq) {
        int krow = kvbase + 4 * (cq & 1) + 32 * (cq >> 1);
        kf[cq][0] = *(const short8*)(base + krow * 64 + ((8 * g) ^ ksw));
        kf[cq][1] = *(const short8*)(base + krow * 64 + ((8 * g + 32) ^ ksw));
      }
      __builtin_amdgcn_s_setprio(1);
#pragma unroll
      for (int cq = 0; cq < 4; ++cq) {
        f32x4 z = (f32x4)(0.0f);
        z = __builtin_amdgcn_mfma_f32_16x16x32_bf16(kf[cq][0], fq0, z, 0, 0, 0);
        z = __builtin_amdgcn_mfma_f32_16x16x32_bf16(kf[cq][1], fq1, z, 0, 0, 0);
        sc[cq] = z;
      }
      __builtin_amdgcn_s_setprio(0);
    }

    // causal mask (diag tile only); sc[cq][j] is kv = kv0+8g+4(cq&1)+32(cq>>1)+j
    if (t == qt) {
#pragma unroll
      for (int cq = 0; cq < 4; ++cq) {
        int kvc = kv0 + 8 * g + 4 * (cq & 1) + 32 * (cq >> 1);
#pragma unroll
        for (int j = 0; j < 4; ++j)
          if (kvc + j > qrow) sc[cq][j] = -1e30f;
      }
    }

    // row max: 15 in-reg + 2 shfl (lanes l15, +16, +32, +48 share q)
    float vmax = sc[0][0];
#pragma unroll
    for (int cq = 0; cq < 4; ++cq)
#pragma unroll
      for (int j = 0; j < 4; ++j) vmax = fmaxf(vmax, sc[cq][j]);
    vmax = fmaxf(vmax, __shfl_xor(vmax, 16));
    vmax = fmaxf(vmax, __shfl_xor(vmax, 32));

    // defer-max (T13): raw-score threshold 44 -> p bounded by ~2^8
    if (!__all(vmax - m_run <= 44.0f)) {
      float mnew = fmaxf(m_run, vmax);
      float alpha = exp2f((m_run - mnew) * CEXP);
      l_part *= alpha;
#pragma unroll
      for (int c2 = 0; c2 < 4; ++c2)
#pragma unroll
        for (int j = 0; j < 4; ++j) oacc[c2][j] *= alpha;
      m_run = mnew;
    }

    // exp + PARTIAL row sum (reduced once in epilogue)
#pragma unroll
    for (int cq = 0; cq < 4; ++cq)
#pragma unroll
      for (int j = 0; j < 4; ++j) {
        float p = exp2f((sc[cq][j] - m_run) * CEXP);
        sc[cq][j] = p;
        l_part += p;
      }

    // pack P in-register -> PV B-fragments (kv = 32h+8g+m; m = 4(cq&1)+j)
    union { short8 s8; uint32_t w[4]; } pa[2];
#pragma unroll
    for (int h = 0; h < 2; ++h)
#pragma unroll
      for (int i = 0; i < 4; ++i) {
        float lo = sc[2 * h + (i >> 1)][(i & 1) * 2];
        float hi = sc[2 * h + (i >> 1)][(i & 1) * 2 + 1];
        asm("v_cvt_pk_bf16_f32 %0, %1, %2" : "=v"(pa[h].w[i]) : "v"(lo), "v"(hi));
      }

    // PV: O^T[d][q] += V^T-frag (A, rows=d) x P-frag (B, rows=q), from Vt[cur]
    __builtin_amdgcn_s_setprio(1);
#pragma unroll
    for (int c2 = 0; c2 < 4; ++c2)
#pragma unroll
      for (int h = 0; h < 2; ++h) {
        short8 av = *(const short8*)(&Vt[cur][0][0] + (c2 * 16 + l15) * 64 +
                                     ((h * 32 + 8 * g) ^ vsw));
        oacc[c2] = __builtin_amdgcn_mfma_f32_16x16x32_bf16(av, pa[h].s8,
                                                           oacc[c2], 0, 0, 0);
      }
    __builtin_amdgcn_s_setprio(0);

    // write staged K(t+1), V(t+1) into the other buffers, single barrier
    if (t < qt) {
#pragma unroll
      for (int i = 0; i < 2; ++i) {
        int rw = krow_st + i * 8;
        int wsw = (((rw & 3) | (((rw >> 3) & 1) << 2)) << 3);
        *(short8*)(&Ks[cur ^ 1][0][0] + rw * 64 + (kcol_st ^ wsw)) = ktmp[i];
      }
#pragma unroll
      for (int it2 = 0; it2 < 2; ++it2) {
        short8 w;
#pragma unroll
        for (int i = 0; i < 8; ++i) w[i] = (short)vtmp[it2 * 8 + i];
        int kvb = wid * 8 + it2 * 32;
        *(short8*)(&Vt[cur ^ 1][0][0] + lane * 64 + (kvb ^ ((lane & 7) << 3))) = w;
      }
    }
    __syncthreads();
  }

  // epilogue: reduce l across the 4 lanes sharing a q-row, normalize,
  // transpose through LDS (per-wave 16x64 region of Vt[0]), coalesced store
  float ls = l_part;
  ls += __shfl_xor(ls, 16);
  ls += __shfl_xor(ls, 32);
  float inv = 1.0f / ls;
  u16* ow = &Vt[0][0][0] + wid * 16 * 64;       // 16 rows x 64 per wave
#pragma unroll
  for (int c2 = 0; c2 < 4; ++c2)
#pragma unroll
    for (int jp = 0; jp < 2; ++jp) {
      float lo = oacc[c2][2 * jp] * inv, hi = oacc[c2][2 * jp + 1] * inv;
      uint32_t w;
      asm("v_cvt_pk_bf16_f32 %0, %1, %2" : "=v"(w) : "v"(lo), "v"(hi));
      *(uint32_t*)&ow[l15 * 64 + c2 * 16 + 4 * g + 2 * jp] = w;
    }
  __syncthreads();
  int rr = lane >> 2, dc = (lane & 3) * 16;
  short8 o0 = *(const short8*)&ow[rr * 64 + dc];
  short8 o1 = *(const short8*)&ow[rr * 64 + dc + 8];
  int b = bh >> 4, hh = bh & 15;
  size_t xo = ((size_t)b * SEQ + qw + rr) * EMB + hh * 64 + dc;
  *(short8*)&X[xo] = o0;
  *(short8*)&X[xo + 8] = o1;
}

// ---------------- host ----------------
extern "C" void kernel_launch(void* const* d_in, const int* in_sizes, int n_in,
                              void* d_out, int out_size, void* d_ws, size_t ws_size,
                              hipStream_t stream) {
  const float* q  = (const float*)d_in[0];
  const float* k  = (const float*)d_in[1];
  const float* v  = (const float*)d_in[2];
  const float* wq = (const float*)d_in[4];
  const float* bq = (const float*)d_in[5];
  const float* wk = (const float*)d_in[6];
  const float* bk = (const float*)d_in[7];
  const float* wv = (const float*)d_in[8];
  const float* bv = (const float*)d_in[9];
  const float* wo = (const float*)d_in[10];
  const float* bo = (const float*)d_in[11];

  u16* Wall = (u16*)d_ws;                                 // 4 x [1024,1024] bf16
  u16* QKVh = Wall + (size_t)4 * EMB * EMB;               // 3 x [B,H,S,64] bf16
  u16* Xb   = QKVh + (size_t)3 * MTOT * EMB;              // [4096,1024] bf16

  // weights fp32 -> bf16 (re-read 8x from L2 by the GEMMs, upfront is cheaper)
  cvt_w<<<dim3(EMB * EMB / 4 / 256, 4), 256, 0, stream>>>(wq, wk, wv, wo, Wall);

  // QKV projections with fused fp32->bf16 A-staging (T1 XCD-aware 1D grid)
  gemm_qkv_f32<<<768, 256, 0, stream>>>(q, k, v, Wall, bq, bk, bv, QKVh);

  // flash attention -> Xb [4096,1024] bf16 (v9, 1024 blocks)
  const u16* Qh = QKVh;
  const u16* Kh = QKVh + (size_t)MTOT * EMB;
  const u16* Vh = QKVh + (size_t)2 * MTOT * EMB;
  flash_attn<<<1024, 256, 0, stream>>>(Qh, Kh, Vh, Xb);

  // output projection -> fp32 d_out (T1 XCD-aware 1D grid, BM=64, 512 blocks)
  gemm_out<<<512, 256, 0, stream>>>(Xb, Wall + (size_t)3 * EMB * EMB, bo, (float*)d_out);
}

// Round 21
// 117.829 us; speedup vs baseline: 1.0517x; 1.0086x over previous
//
#include <hip/hip_runtime.h>
#include <stdint.h>

// ---- types ----
typedef __attribute__((ext_vector_type(8))) short short8;   // 8 bf16 (4 VGPRs)
typedef __attribute__((ext_vector_type(4))) float f32x4;    // MFMA acc
typedef unsigned short u16;

// B=2, S=2048, E=1024, H=16, DK=64
#define SEQ 2048
#define EMB 1024
#define NH 16
#define DK 64
#define MTOT 4096   // B*S
#define CEXP 0.18033688011112042f   // 0.125 * log2(e): fold qk-scale into exp2

__device__ __forceinline__ u16 f2bf(float f) {
  union { float f; unsigned int u; } x; x.f = f;
  unsigned int r = x.u + 0x7fffu + ((x.u >> 16) & 1u);  // RNE
  return (u16)(r >> 16);
}

// async global->LDS, 16B per lane. LDS dest = wave-uniform base + lane*16.
__device__ __forceinline__ void gload_lds16(const void* g, void* l) {
  __builtin_amdgcn_global_load_lds(
      (const __attribute__((address_space(1))) unsigned int*)g,
      (__attribute__((address_space(3))) unsigned int*)l,
      16, 0, 0);
}

// ---------------- fp32 -> bf16 convert: WEIGHTS ONLY ----------------
__global__ __launch_bounds__(256) void cvt_w(const float* __restrict__ a,
                                             const float* __restrict__ b,
                                             const float* __restrict__ c,
                                             const float* __restrict__ e,
                                             u16* __restrict__ d) {
  const float* s = (blockIdx.y == 0) ? a
                 : ((blockIdx.y == 1) ? b : ((blockIdx.y == 2) ? c : e));
  size_t base = (size_t)blockIdx.y * ((size_t)EMB * EMB / 4);
  int i = blockIdx.x * 256 + threadIdx.x;
  float4 v = ((const float4*)s)[i];
  ushort4 o;
  o.x = f2bf(v.x); o.y = f2bf(v.y); o.z = f2bf(v.z); o.w = f2bf(v.w);
  ((ushort4*)d)[base + i] = o;
}

// ------- gemm_qkv v4: A staged as FP32 via async gload_lds -------
// R17/R18 lesson: reg-staged A pays a ~600cy synchronous wait per K-step
// (hipcc drains vmcnt at barriers so prefetch can't cross). v4 routes A
// through gload_lds like B (latency absorbed by the single barrier drain)
// and converts fp32->bf16 at FRAGMENT-LOAD time (2 ds_read_b128 + 4 cvt_pk
// per (mi,kk)). Asf [128][64] fp32 uses a 16B-slot swizzle s = c16^(row&7);
// gload_lds writes are linear so the swizzle is applied to the GLOBAL source
// address (m173 pattern; involution => reads with the same XOR are correct).
// Per ds_read: 8 lanes per 4-bank set = the 1KB/instr LDS floor (no conflict).
// LDS 48KB -> 3 blocks/CU unchanged.
__global__ __launch_bounds__(256, 3) void gemm_qkv_f32(const float* __restrict__ qf,
                                                       const float* __restrict__ kf,
                                                       const float* __restrict__ vf,
                                                       const u16* __restrict__ Wall,
                                                       const float* __restrict__ bq,
                                                       const float* __restrict__ bk,
                                                       const float* __restrict__ bv,
                                                       u16* __restrict__ QKVh) {
  __shared__ __align__(16) float Asf[128 * 16 * 4];   // 128 rows x 16 slots x 4 f32
  __shared__ __align__(16) u16 Bs[128 * 64];

  int bl = blockIdx.x;
  int xcd = bl & 7, i0 = bl >> 3;
  int bx = i0 & 7;                // n-panel
  int j = i0 >> 3;                // [0,12): 4 m-panels x 3 z per XCD
  int z = j >> 2;
  int by = xcd * 4 + (j & 3);
  const float* A = (z == 0) ? qf : ((z == 1) ? kf : vf);
  const u16* W = Wall + (size_t)z * EMB * EMB;
  const float* bias = (z == 0) ? bq : ((z == 1) ? bk : bv);
  u16* dst = QKVh + (size_t)z * MTOT * EMB;
  int m0 = by * 128, n0 = bx * 128;

  const int K = EMB;
  int tid = threadIdx.x, lane = tid & 63, wid = tid >> 6;
  int g = lane >> 4, l15 = lane & 15;
  int wr = wid >> 1, wc = wid & 1;

  f32x4 acc[4][4];
#pragma unroll
  for (int mi = 0; mi < 4; ++mi)
#pragma unroll
    for (int ni = 0; ni < 4; ++ni) acc[mi][ni] = (f32x4)(0.0f);

  for (int kt = 0; kt < K / 64; ++kt) {
    int k0 = kt * 64;

    // --- A tile fp32 via gload_lds: 8 instrs/wave, pre-swizzled source ---
    // slotIdx = (wid*8+i)*64 + lane; row = slotIdx>>4, c16w = slotIdx&15.
    // LDS linear dest; global col16 = c16w ^ (row&7).
#pragma unroll
    for (int i = 0; i < 8; ++i) {
      int slot = (wid * 8 + i) * 64 + lane;
      int row = slot >> 4, c16w = slot & 15;
      int c16g = c16w ^ (row & 7);
      gload_lds16(A + (size_t)(m0 + row) * K + k0 + c16g * 4,
                  (char*)Asf + (size_t)slot * 16);
    }
    // --- B tile via async gload_lds (4 instrs per wave) ---
#pragma unroll
    for (int i = 0; i < 4; ++i) {
      int off = (wid * 4 + i) * 1024;          // byte offset into tile
      int elem = (off >> 1) + lane * 8;
      int row = elem >> 6, col = elem & 63;
      gload_lds16(W + (size_t)(n0 + row) * K + k0 + col, (char*)Bs + off);
    }
    __syncthreads();  // single drain for A + B
#pragma unroll
    for (int kk = 0; kk < 2; ++kk) {
      short8 af[4], bf[4];
#pragma unroll
      for (int mi = 0; mi < 4; ++mi) {
        int row = wr * 64 + mi * 16 + l15;
        int c16 = kk * 8 + 2 * g;              // f32 16B-slot base for k=kk*32+8g
        int sw = row & 7;
        f32x4 f0 = *(const f32x4*)&Asf[(row * 16 + (c16 ^ sw)) * 4];
        f32x4 f1 = *(const f32x4*)&Asf[(row * 16 + ((c16 + 1) ^ sw)) * 4];
        union { short8 s8; uint32_t w[4]; } pk;
        asm("v_cvt_pk_bf16_f32 %0, %1, %2" : "=v"(pk.w[0]) : "v"(f0[0]), "v"(f0[1]));
        asm("v_cvt_pk_bf16_f32 %0, %1, %2" : "=v"(pk.w[1]) : "v"(f0[2]), "v"(f0[3]));
        asm("v_cvt_pk_bf16_f32 %0, %1, %2" : "=v"(pk.w[2]) : "v"(f1[0]), "v"(f1[1]));
        asm("v_cvt_pk_bf16_f32 %0, %1, %2" : "=v"(pk.w[3]) : "v"(f1[2]), "v"(f1[3]));
        af[mi] = pk.s8;
      }
#pragma unroll
      for (int ni = 0; ni < 4; ++ni)
        bf[ni] = *(const short8*)&Bs[(wc * 64 + ni * 16 + l15) * 64 + kk * 32 + 8 * g];
#pragma unroll
      for (int mi = 0; mi < 4; ++mi)
#pragma unroll
        for (int ni = 0; ni < 4; ++ni)
          acc[mi][ni] = __builtin_amdgcn_mfma_f32_16x16x32_bf16(af[mi], bf[ni],
                                                                acc[mi][ni], 0, 0, 0);
    }
    __syncthreads();
  }

  // epilogue: D layout col=lane&15, row=(lane>>4)*4+j; store head layout bf16
#pragma unroll
  for (int ni = 0; ni < 4; ++ni) {
    int n_g = n0 + wc * 64 + ni * 16 + l15;
    float bv2 = bias[n_g];
#pragma unroll
    for (int mi = 0; mi < 4; ++mi) {
#pragma unroll
      for (int j2 = 0; j2 < 4; ++j2) {
        int m_g = m0 + wr * 64 + mi * 16 + 4 * g + j2;
        float v = acc[mi][ni][j2] + bv2;
        int b = m_g >> 11, s = m_g & (SEQ - 1);
        int h = n_g >> 6, d = n_g & 63;
        dst[((((size_t)b * NH + h) * SEQ + s) << 6) + d] = f2bf(v);
      }
    }
  }
}

// ---------------- gemm_out: C fp32 = X bf16 @ Wo^T + bias, BM=64 ------------
// (exact R20 kernel: 512 blocks = 2 blocks/CU, wave-tile 32x64.)
__global__ __launch_bounds__(256, 4) void gemm_out(const u16* __restrict__ X,
                                                   const u16* __restrict__ Wo,
                                                   const float* __restrict__ bo,
                                                   float* __restrict__ out) {
  __shared__ __align__(16) u16 As[64 * 64];
  __shared__ __align__(16) u16 Bs[128 * 64];
  int bl = blockIdx.x;
  int xcd = bl & 7, i0 = bl >> 3;               // i0 in [0,64)
  int bx = i0 & 7;                              // n-panel
  int by = xcd * 8 + (i0 >> 3);                 // m-panel 0..63, 8 per XCD
  int m0 = by * 64, n0 = bx * 128;

  const int K = EMB;
  int tid = threadIdx.x, lane = tid & 63, wid = tid >> 6;
  int g = lane >> 4, l15 = lane & 15;
  int wr = wid >> 1, wc = wid & 1;              // wave-tile 32x64 at (wr,wc)

  f32x4 acc[2][4];
#pragma unroll
  for (int mi = 0; mi < 2; ++mi)
#pragma unroll
    for (int ni = 0; ni < 4; ++ni) acc[mi][ni] = (f32x4)(0.0f);

  for (int kt = 0; kt < K / 64; ++kt) {
    int k0 = kt * 64;
#pragma unroll
    for (int i = 0; i < 2; ++i) {
      int off = (wid * 2 + i) * 1024;
      int elem = (off >> 1) + lane * 8;
      int row = elem >> 6, col = elem & 63;
      gload_lds16(X + (size_t)(m0 + row) * K + k0 + col, (char*)As + off);
    }
#pragma unroll
    for (int i = 0; i < 4; ++i) {
      int off = (wid * 4 + i) * 1024;
      int elem = (off >> 1) + lane * 8;
      int row = elem >> 6, col = elem & 63;
      gload_lds16(Wo + (size_t)(n0 + row) * K + k0 + col, (char*)Bs + off);
    }
    __syncthreads();
#pragma unroll
    for (int kk = 0; kk < 2; ++kk) {
      short8 af[2], bf[4];
#pragma unroll
      for (int mi = 0; mi < 2; ++mi)
        af[mi] = *(const short8*)&As[(wr * 32 + mi * 16 + l15) * 64 + kk * 32 + 8 * g];
#pragma unroll
      for (int ni = 0; ni < 4; ++ni)
        bf[ni] = *(const short8*)&Bs[(wc * 64 + ni * 16 + l15) * 64 + kk * 32 + 8 * g];
#pragma unroll
      for (int mi = 0; mi < 2; ++mi)
#pragma unroll
        for (int ni = 0; ni < 4; ++ni)
          acc[mi][ni] = __builtin_amdgcn_mfma_f32_16x16x32_bf16(af[mi], bf[ni],
                                                                acc[mi][ni], 0, 0, 0);
    }
    __syncthreads();
  }

#pragma unroll
  for (int ni = 0; ni < 4; ++ni) {
    int n_g = n0 + wc * 64 + ni * 16 + l15;
    float bv = bo[n_g];
#pragma unroll
    for (int mi = 0; mi < 2; ++mi) {
#pragma unroll
      for (int j = 0; j < 4; ++j) {
        int m_g = m0 + wr * 32 + mi * 16 + 4 * g + j;
        out[(size_t)m_g * EMB + n_g] = acc[mi][ni][j] + bv;
      }
    }
  }
}

// ---------------- flash attention (causal), v9 (exact R10/R11 kernel) -------
__global__ __launch_bounds__(256, 4) void flash_attn(const u16* __restrict__ Qh,
                                                     const u16* __restrict__ Kh,
                                                     const u16* __restrict__ Vh,
                                                     u16* __restrict__ X) {
  __shared__ __align__(16) u16 Ks[2][64][64];   // [buf][kv][k], swz_k
  __shared__ __align__(16) u16 Vt[2][64][64];   // [buf][d][kv], swz_v

  int tid = threadIdx.x, lane = tid & 63, wid = tid >> 6;
  int g = lane >> 4, l15 = lane & 15;

  int bl = blockIdx.x;
  int xcd = bl & 7, idx = bl >> 3;
  int c = idx & 31, r = idx >> 5;
  int bh = xcd * 4 + r;                         // 4 bh per XCD -> K/V L2-resident
  int cc = (r >= 2) ? ((c + 16) & 31) : c;
  int qt = (r & 1) ? (31 - cc) : cc;            // balanced qt per CU slot

  int q0 = qt * 64, qw = q0 + wid * 16;
  int qrow = qw + l15;                          // this lane's q row

  // Q fragment (B-operand): rows q = qw+l15, k halves at +0 / +32
  const short8* qp = (const short8*)(Qh + ((size_t)bh * SEQ + qrow) * DK + 8 * g);
  short8 fq0 = qp[0], fq1 = qp[4];

  int kvbase = 8 * (l15 >> 2) + (l15 & 3);      // sigma row base for this lane
  int ksw = ((l15 & 3) | (((l15 >> 2) & 1) << 2)) << 3;   // u16 col XOR
  int vsw = (l15 & 7) << 3;                               // PV-read XOR
  const u16* Kb = Kh + (size_t)bh * SEQ * DK;
  const u16* Vb = Vh + (size_t)bh * SEQ * DK;

  // K staging geometry: 2 instrs/wave; lane covers row rw, 16B chunk (lane&7)
  int krow_st = wid * 16 + (lane >> 3);         // +8*i for i=0,1
  int kcol_st = (lane & 7) * 8;                 // u16 col (pre-swizzle)

  f32x4 sc[4], oacc[4];
#pragma unroll
  for (int i = 0; i < 4; ++i) oacc[i] = (f32x4)(0.0f);
  float m_run = -1e30f, l_part = 0.0f;

  // prologue: stage K(0), V(0) into buf 0
#pragma unroll
  for (int i = 0; i < 2; ++i) {
    int rw = krow_st + i * 8;
    int wsw = (((rw & 3) | (((rw >> 3) & 1) << 2)) << 3);
    short8 kt = *(const short8*)(Kb + (size_t)rw * DK + kcol_st);
    *(short8*)(&Ks[0][0][0] + rw * 64 + (kcol_st ^ wsw)) = kt;
  }
#pragma unroll
  for (int it2 = 0; it2 < 2; ++it2) {
    int kvb = wid * 8 + it2 * 32;
    short8 tmp;
#pragma unroll
    for (int i = 0; i < 8; ++i)
      tmp[i] = (short)Vb[(size_t)(kvb + i) * DK + lane];
    *(short8*)(&Vt[0][0][0] + lane * 64 + (kvb ^ ((lane & 7) << 3))) = tmp;
  }
  __syncthreads();

  for (int t = 0; t <= qt; ++t) {
    int kv0 = t * 64;
    int cur = t & 1;

    // T14: issue next-tile K + V global loads FIRST (hide under compute)
    short8 ktmp[2];
    u16 vtmp[16];
    if (t < qt) {
      int kvn = kv0 + 64;
#pragma unroll
      for (int i = 0; i < 2; ++i)
        ktmp[i] = *(const short8*)(Kb + (size_t)(kvn + krow_st + i * 8) * DK + kcol_st);
#pragma unroll
      for (int it2 = 0; it2 < 2; ++it2)
#pragma unroll
        for (int i = 0; i < 8; ++i)
          vtmp[it2 * 8 + i] = Vb[(size_t)(kvn + wid * 8 + it2 * 32 + i) * DK + lane];
    }

    // QK^T swapped from Ks[cur] (sigma rows; swizzled, conflict-free b128)
    {
      const u16* base = &Ks[cur][0][0];
      short8 kf[4][2];
#pragma unroll
      for (int cq = 0; cq < 4; ++cq) {
        int krow = kvbase + 4 * (cq & 1) + 32 * (cq >> 1);
        kf[cq][0] = *(const short8*)(base + krow * 64 + ((8 * g) ^ ksw));
        kf[cq][1] = *(const short8*)(base + krow * 64 + ((8 * g + 32) ^ ksw));
      }
      __builtin_amdgcn_s_setprio(1);
#pragma unroll
      for (int cq = 0; cq < 4; ++cq) {
        f32x4 z = (f32x4)(0.0f);
        z = __builtin_amdgcn_mfma_f32_16x16x32_bf16(kf[cq][0], fq0, z, 0, 0, 0);
        z = __builtin_amdgcn_mfma_f32_16x16x32_bf16(kf[cq][1], fq1, z, 0, 0, 0);
        sc[cq] = z;
      }
      __builtin_amdgcn_s_setprio(0);
    }

    // causal mask (diag tile only); sc[cq][j] is kv = kv0+8g+4(cq&1)+32(cq>>1)+j
    if (t == qt) {
#pragma unroll
      for (int cq = 0; cq < 4; ++cq) {
        int kvc = kv0 + 8 * g + 4 * (cq & 1) + 32 * (cq >> 1);
#pragma unroll
        for (int j = 0; j < 4; ++j)
          if (kvc + j > qrow) sc[cq][j] = -1e30f;
      }
    }

    // row max: 15 in-reg + 2 shfl (lanes l15, +16, +32, +48 share q)
    float vmax = sc[0][0];
#pragma unroll
    for (int cq = 0; cq < 4; ++cq)
#pragma unroll
      for (int j = 0; j < 4; ++j) vmax = fmaxf(vmax, sc[cq][j]);
    vmax = fmaxf(vmax, __shfl_xor(vmax, 16));
    vmax = fmaxf(vmax, __shfl_xor(vmax, 32));

    // defer-max (T13): raw-score threshold 44 -> p bounded by ~2^8
    if (!__all(vmax - m_run <= 44.0f)) {
      float mnew = fmaxf(m_run, vmax);
      float alpha = exp2f((m_run - mnew) * CEXP);
      l_part *= alpha;
#pragma unroll
      for (int c2 = 0; c2 < 4; ++c2)
#pragma unroll
        for (int j = 0; j < 4; ++j) oacc[c2][j] *= alpha;
      m_run = mnew;
    }

    // exp + PARTIAL row sum (reduced once in epilogue)
#pragma unroll
    for (int cq = 0; cq < 4; ++cq)
#pragma unroll
      for (int j = 0; j < 4; ++j) {
        float p = exp2f((sc[cq][j] - m_run) * CEXP);
        sc[cq][j] = p;
        l_part += p;
      }

    // pack P in-register -> PV B-fragments (kv = 32h+8g+m; m = 4(cq&1)+j)
    union { short8 s8; uint32_t w[4]; } pa[2];
#pragma unroll
    for (int h = 0; h < 2; ++h)
#pragma unroll
      for (int i = 0; i < 4; ++i) {
        float lo = sc[2 * h + (i >> 1)][(i & 1) * 2];
        float hi = sc[2 * h + (i >> 1)][(i & 1) * 2 + 1];
        asm("v_cvt_pk_bf16_f32 %0, %1, %2" : "=v"(pa[h].w[i]) : "v"(lo), "v"(hi));
      }

    // PV: O^T[d][q] += V^T-frag (A, rows=d) x P-frag (B, rows=q), from Vt[cur]
    __builtin_amdgcn_s_setprio(1);
#pragma unroll
    for (int c2 = 0; c2 < 4; ++c2)
#pragma unroll
      for (int h = 0; h < 2; ++h) {
        short8 av = *(const short8*)(&Vt[cur][0][0] + (c2 * 16 + l15) * 64 +
                                     ((h * 32 + 8 * g) ^ vsw));
        oacc[c2] = __builtin_amdgcn_mfma_f32_16x16x32_bf16(av, pa[h].s8,
                                                           oacc[c2], 0, 0, 0);
      }
    __builtin_amdgcn_s_setprio(0);

    // write staged K(t+1), V(t+1) into the other buffers, single barrier
    if (t < qt) {
#pragma unroll
      for (int i = 0; i < 2; ++i) {
        int rw = krow_st + i * 8;
        int wsw = (((rw & 3) | (((rw >> 3) & 1) << 2)) << 3);
        *(short8*)(&Ks[cur ^ 1][0][0] + rw * 64 + (kcol_st ^ wsw)) = ktmp[i];
      }
#pragma unroll
      for (int it2 = 0; it2 < 2; ++it2) {
        short8 w;
#pragma unroll
        for (int i = 0; i < 8; ++i) w[i] = (short)vtmp[it2 * 8 + i];
        int kvb = wid * 8 + it2 * 32;
        *(short8*)(&Vt[cur ^ 1][0][0] + lane * 64 + (kvb ^ ((lane & 7) << 3))) = w;
      }
    }
    __syncthreads();
  }

  // epilogue: reduce l across the 4 lanes sharing a q-row, normalize,
  // transpose through LDS (per-wave 16x64 region of Vt[0]), coalesced store
  float ls = l_part;
  ls += __shfl_xor(ls, 16);
  ls += __shfl_xor(ls, 32);
  float inv = 1.0f / ls;
  u16* ow = &Vt[0][0][0] + wid * 16 * 64;       // 16 rows x 64 per wave
#pragma unroll
  for (int c2 = 0; c2 < 4; ++c2)
#pragma unroll
    for (int jp = 0; jp < 2; ++jp) {
      float lo = oacc[c2][2 * jp] * inv, hi = oacc[c2][2 * jp + 1] * inv;
      uint32_t w;
      asm("v_cvt_pk_bf16_f32 %0, %1, %2" : "=v"(w) : "v"(lo), "v"(hi));
      *(uint32_t*)&ow[l15 * 64 + c2 * 16 + 4 * g + 2 * jp] = w;
    }
  __syncthreads();
  int rr = lane >> 2, dc = (lane & 3) * 16;
  short8 o0 = *(const short8*)&ow[rr * 64 + dc];
  short8 o1 = *(const short8*)&ow[rr * 64 + dc + 8];
  int b = bh >> 4, hh = bh & 15;
  size_t xo = ((size_t)b * SEQ + qw + rr) * EMB + hh * 64 + dc;
  *(short8*)&X[xo] = o0;
  *(short8*)&X[xo + 8] = o1;
}

// ---------------- host ----------------
extern "C" void kernel_launch(void* const* d_in, const int* in_sizes, int n_in,
                              void* d_out, int out_size, void* d_ws, size_t ws_size,
                              hipStream_t stream) {
  const float* q  = (const float*)d_in[0];
  const float* k  = (const float*)d_in[1];
  const float* v  = (const float*)d_in[2];
  const float* wq = (const float*)d_in[4];
  const float* bq = (const float*)d_in[5];
  const float* wk = (const float*)d_in[6];
  const float* bk = (const float*)d_in[7];
  const float* wv = (const float*)d_in[8];
  const float* bv = (const float*)d_in[9];
  const float* wo = (const float*)d_in[10];
  const float* bo = (const float*)d_in[11];

  u16* Wall = (u16*)d_ws;                                 // 4 x [1024,1024] bf16
  u16* QKVh = Wall + (size_t)4 * EMB * EMB;               // 3 x [B,H,S,64] bf16
  u16* Xb   = QKVh + (size_t)3 * MTOT * EMB;              // [4096,1024] bf16

  // weights fp32 -> bf16 (re-read 8x from L2 by the GEMMs, upfront is cheaper)
  cvt_w<<<dim3(EMB * EMB / 4 / 256, 4), 256, 0, stream>>>(wq, wk, wv, wo, Wall);

  // QKV projections, A staged fp32 via gload_lds (T1 XCD-aware 1D grid)
  gemm_qkv_f32<<<768, 256, 0, stream>>>(q, k, v, Wall, bq, bk, bv, QKVh);

  // flash attention -> Xb [4096,1024] bf16 (v9, 1024 blocks)
  const u16* Qh = QKVh;
  const u16* Kh = QKVh + (size_t)MTOT * EMB;
  const u16* Vh = QKVh + (size_t)2 * MTOT * EMB;
  flash_attn<<<1024, 256, 0, stream>>>(Qh, Kh, Vh, Xb);

  // output projection -> fp32 d_out (T1 XCD-aware 1D grid, BM=64, 512 blocks)
  gemm_out<<<512, 256, 0, stream>>>(Xb, Wall + (size_t)3 * EMB * EMB, bo, (float*)d_out);
}